// Round 10
// baseline (2907.387 us; speedup 1.0000x reference)
//
#include <hip/hip_runtime.h>
#include <hip/hip_fp16.h>

#define B_    128
#define T_    1024
#define NTH   256
#define NVP   32   // f16 pairs/row in arch VGPRs (pairs  0..31,  h-quads 0..7)
#define NAP   60   // f16 pairs/row in AGPRs      (pairs 32..91,  h-quads 8..22)
#define NLP   36   // f16 pairs/row in LDS        (pairs 92..127, h-quads 23..31)
#define NQV   8    // h-quads for VGPR part
#define NQA   15   // h-quads for AGPR part
#define NQL   9    // LDS quads per row

typedef _Float16 half2_t __attribute__((ext_vector_type(2)));

__device__ __forceinline__ float fdot2(unsigned int w, unsigned int h, float acc) {
    return __builtin_amdgcn_fdot2(__builtin_bit_cast(half2_t, w),
                                  __builtin_bit_cast(half2_t, h), acc, false);
}
__device__ __forceinline__ unsigned int packf16(float a, float b) {
    half2_t h;
    h.x = (_Float16)a;
    h.y = (_Float16)b;
    return __builtin_bit_cast(unsigned int, h);
}
// Explicit AGPR residency. VOP3P v_dot2 can NOT source "a" regs directly
// (round 8) -- bounce through v_accvgpr_read.
#define AGPR_WRITE(dst, src) \
    asm volatile("v_accvgpr_write_b32 %0, %1" : "=a"(dst) : "v"(src))
#define AGPR_READ(dst, src) \
    asm volatile("v_accvgpr_read_b32 %0, %1" : "=v"(dst) : "a"(src))

// ---------------------------------------------------------------------------
// Kernel 1: persistent LSTM. 1 block/batch, 256 threads, 1 wave/SIMD.
// Thread u owns all 4 gate rows of unit u -> thread-local activation,
// 1 barrier/step. Round-7/9 lesson: allocator keeps only ~95 long-lived
// arch-VGPR weights; so arch gets just 128 (margin for transients), AGPR
// gets 240 of 256, LDS the remaining 144 KB. Expect zero scratch.
// ---------------------------------------------------------------------------
__global__ __attribute__((amdgpu_flat_work_group_size(NTH, NTH),
                          amdgpu_waves_per_eu(1, 1)))
void lstm_k(const float* __restrict__ x, const float* __restrict__ w_ih,
            const float* __restrict__ w_hh, const float* __restrict__ b_ih,
            const float* __restrict__ b_hh, unsigned int* __restrict__ hT_p) {
    extern __shared__ unsigned char smem[];
    uint4*        w_lds4 = (uint4*)smem;                       // [36][256] quads = 144 KB
    unsigned int* hbuf   = (unsigned int*)(smem + 147456);     // [2][128] packed f16 pairs
    float*        xseq   = (float*)(smem + 147456 + 1024);     // [1024]

    const int u = threadIdx.x;
    const int b = blockIdx.x;

    float bs[4], wi[4];
#pragma unroll
    for (int g = 0; g < 4; ++g) {
        const int r = g * 256 + u;
        bs[g] = b_ih[r] + b_hh[r];
        wi[g] = w_ih[r];
    }

    // xseq[t] = x[b, (t%512)*2 + t/512]
    for (int t = u; t < T_; t += NTH)
        xseq[t] = x[b * T_ + ((t & 511) << 1) + (t >> 9)];

    // ---- weights: arch-VGPR part, pairs [0, NVP) ----
    unsigned int wv[4][NVP];
#pragma unroll
    for (int g = 0; g < 4; ++g) {
        const float* row = &w_hh[(size_t)(g * 256 + u) * 256];
#pragma unroll
        for (int p = 0; p < NVP; p += 2) {
            float4 a4 = *(const float4*)&row[2 * p];
            wv[g][p]     = packf16(a4.x, a4.y);
            wv[g][p + 1] = packf16(a4.z, a4.w);
        }
    }
    // ---- weights: AGPR part, pairs [NVP, NVP+NAP) ----
    unsigned int wa[4][NAP];
#pragma unroll
    for (int g = 0; g < 4; ++g) {
        const float* row = &w_hh[(size_t)(g * 256 + u) * 256];
#pragma unroll
        for (int p = 0; p < NAP; p += 2) {
            float4 a4 = *(const float4*)&row[2 * (NVP + p)];
            unsigned int t0 = packf16(a4.x, a4.y);
            unsigned int t1 = packf16(a4.z, a4.w);
            AGPR_WRITE(wa[g][p], t0);
            AGPR_WRITE(wa[g][p + 1], t1);
        }
    }
    // ---- weights: LDS part, pairs [NVP+NAP, 128) -> quad (g*NQL+j), lane u ----
#pragma unroll
    for (int g = 0; g < 4; ++g) {
#pragma unroll
        for (int j = 0; j < NQL; ++j) {
            const float* src = &w_hh[(size_t)(g * 256 + u) * 256 + 2 * (NVP + NAP) + 8 * j];
            float4 a4 = ((const float4*)src)[0];
            float4 c4 = ((const float4*)src)[1];
            uint4 pk;
            pk.x = packf16(a4.x, a4.y); pk.y = packf16(a4.z, a4.w);
            pk.z = packf16(c4.x, c4.y); pk.w = packf16(c4.z, c4.w);
            w_lds4[(g * NQL + j) * 256 + u] = pk;
        }
    }
    if (u < 128) { hbuf[u] = 0u; hbuf[128 + u] = 0u; }
    float c_state = 0.f;
    __syncthreads();

    for (int t = 0; t < T_; ++t) {
        const uint4* h4 = (const uint4*)&hbuf[(t & 1) * 128];
        const float  xt = xseq[t];
        float a0[4], a1[4];
#pragma unroll
        for (int g = 0; g < 4; ++g) {
            a0[g] = fmaf(xt, wi[g], bs[g]);
            a1[g] = 0.f;
        }
        // --- window 1: VGPR quads 0..7 ---
#pragma unroll
        for (int q = 0; q < NQV; ++q) {
            uint4 hp = h4[q];
#pragma unroll
            for (int g = 0; g < 4; ++g) {
                a0[g] = fdot2(wv[g][4 * q + 0], hp.x, a0[g]);
                a1[g] = fdot2(wv[g][4 * q + 1], hp.y, a1[g]);
                a0[g] = fdot2(wv[g][4 * q + 2], hp.z, a0[g]);
                a1[g] = fdot2(wv[g][4 * q + 3], hp.w, a1[g]);
            }
        }
        __builtin_amdgcn_sched_barrier(0);
        // --- window 2a: AGPR quads 0..7 ---
#pragma unroll
        for (int q = 0; q < 8; ++q) {
            uint4 hp = h4[NQV + q];
#pragma unroll
            for (int g = 0; g < 4; ++g) {
                unsigned int w0, w1, w2, w3;
                AGPR_READ(w0, wa[g][4 * q + 0]);
                a0[g] = fdot2(w0, hp.x, a0[g]);
                AGPR_READ(w1, wa[g][4 * q + 1]);
                a1[g] = fdot2(w1, hp.y, a1[g]);
                AGPR_READ(w2, wa[g][4 * q + 2]);
                a0[g] = fdot2(w2, hp.z, a0[g]);
                AGPR_READ(w3, wa[g][4 * q + 3]);
                a1[g] = fdot2(w3, hp.w, a1[g]);
            }
        }
        __builtin_amdgcn_sched_barrier(0);
        // --- window 2b: AGPR quads 8..14 ---
#pragma unroll
        for (int q = 8; q < NQA; ++q) {
            uint4 hp = h4[NQV + q];
#pragma unroll
            for (int g = 0; g < 4; ++g) {
                unsigned int w0, w1, w2, w3;
                AGPR_READ(w0, wa[g][4 * q + 0]);
                a0[g] = fdot2(w0, hp.x, a0[g]);
                AGPR_READ(w1, wa[g][4 * q + 1]);
                a1[g] = fdot2(w1, hp.y, a1[g]);
                AGPR_READ(w2, wa[g][4 * q + 2]);
                a0[g] = fdot2(w2, hp.z, a0[g]);
                AGPR_READ(w3, wa[g][4 * q + 3]);
                a1[g] = fdot2(w3, hp.w, a1[g]);
            }
        }
        __builtin_amdgcn_sched_barrier(0);
        // --- window 3a: LDS quads 23..26 ---
#pragma unroll
        for (int j = 0; j < 4; ++j) {
            uint4 hp = h4[NQV + NQA + j];
#pragma unroll
            for (int g = 0; g < 4; ++g) {
                uint4 wq = w_lds4[(g * NQL + j) * 256 + u];
                a0[g] = fdot2(wq.x, hp.x, a0[g]);
                a1[g] = fdot2(wq.y, hp.y, a1[g]);
                a0[g] = fdot2(wq.z, hp.z, a0[g]);
                a1[g] = fdot2(wq.w, hp.w, a1[g]);
            }
        }
        __builtin_amdgcn_sched_barrier(0);
        // --- window 3b: LDS quads 27..31 ---
#pragma unroll
        for (int j = 4; j < NQL; ++j) {
            uint4 hp = h4[NQV + NQA + j];
#pragma unroll
            for (int g = 0; g < 4; ++g) {
                uint4 wq = w_lds4[(g * NQL + j) * 256 + u];
                a0[g] = fdot2(wq.x, hp.x, a0[g]);
                a1[g] = fdot2(wq.y, hp.y, a1[g]);
                a0[g] = fdot2(wq.z, hp.z, a0[g]);
                a1[g] = fdot2(wq.w, hp.w, a1[g]);
            }
        }
        const float gi = a0[0] + a1[0], gf = a0[1] + a1[1];
        const float gg = a0[2] + a1[2], go = a0[3] + a1[3];
        const float i_ = __builtin_amdgcn_rcpf(1.f + __expf(-gi));
        const float f_ = __builtin_amdgcn_rcpf(1.f + __expf(-gf));
        const float g_ = 1.f - 2.f * __builtin_amdgcn_rcpf(__expf(2.f * gg) + 1.f);
        const float o_ = __builtin_amdgcn_rcpf(1.f + __expf(-go));
        c_state = f_ * c_state + i_ * g_;
        const float h = o_ * (1.f - 2.f * __builtin_amdgcn_rcpf(__expf(2.f * c_state) + 1.f));
        ((__half*)&hbuf[((t + 1) & 1) * 128])[u] = __float2half(h);
        __syncthreads();
        if (t >= 512 && u < 128)
            hT_p[(size_t)(((t - 512) << 7) + u) * B_ + b] = hbuf[((t + 1) & 1) * 128 + u];
    }
}

// ---------------------------------------------------------------------------
// Kernel 2: res1 partials, LDS-staged. Grid (16 m-tiles, 32 k-splits),
// 256 threads. w1 packed f16 in LDS; reads wave-uniform b128 broadcasts.
// h reads coalesced. part[(ks*256+m)*128+b].
// ---------------------------------------------------------------------------
#define WST 260
__global__ __launch_bounds__(256, 2) void gemm1_k(
    const unsigned int* __restrict__ hT_p, const float* __restrict__ w1,
    float* __restrict__ part) {
    __shared__ unsigned int w_stage[16 * WST];   // 16.6 KB

    const int tid = threadIdx.x;
    const int m0  = blockIdx.x * 16;
    const int ks  = blockIdx.y;                  // 0..31
    const int bl  = tid & 127;
    const int mg  = tid >> 7;                    // wave-uniform
    const int srow = tid >> 4, slane = tid & 15;

    float acc[8];
#pragma unroll
    for (int j = 0; j < 8; ++j) acc[j] = 0.f;

    const int kbase = ks * 2048;
    for (int s = 0; s < 8; ++s) {
        const int k0 = kbase + s * 256;
        __syncthreads();
        const float* wrow = &w1[(size_t)(m0 + srow) * 131072 + 2 * k0];
#pragma unroll
        for (int i = 0; i < 8; ++i) {
            const int f = slane + 16 * i;
            float4 v = *(const float4*)&wrow[4 * f];
            w_stage[srow * WST + 2 * f]     = packf16(v.x, v.y);
            w_stage[srow * WST + 2 * f + 1] = packf16(v.z, v.w);
        }
        __syncthreads();
#pragma unroll 4
        for (int kg = 0; kg < 64; ++kg) {
            const int kp = 4 * kg;
            unsigned int h0 = hT_p[(size_t)(k0 + kp) * B_ + bl];
            unsigned int h1 = hT_p[(size_t)(k0 + kp + 1) * B_ + bl];
            unsigned int h2 = hT_p[(size_t)(k0 + kp + 2) * B_ + bl];
            unsigned int h3 = hT_p[(size_t)(k0 + kp + 3) * B_ + bl];
#pragma unroll
            for (int j = 0; j < 8; ++j) {
                uint4 w = *(const uint4*)&w_stage[(mg * 8 + j) * WST + kp];
                acc[j] = fdot2(w.x, h0, acc[j]);
                acc[j] = fdot2(w.y, h1, acc[j]);
                acc[j] = fdot2(w.z, h2, acc[j]);
                acc[j] = fdot2(w.w, h3, acc[j]);
            }
        }
    }
#pragma unroll
    for (int j = 0; j < 8; ++j)
        part[(size_t)(ks * 256 + m0 + mg * 8 + j) * B_ + bl] = acc[j];
}

// ---------------------------------------------------------------------------
// Kernel 3: reduce partials over 32 k-splits (+b1, ReLU) -> res1T[m*128+b].
// ---------------------------------------------------------------------------
__global__ __launch_bounds__(128, 8) void reduce_k(
    const float* __restrict__ part, const float* __restrict__ b1,
    float* __restrict__ res1T) {
    const int m = blockIdx.x, bl = threadIdx.x;
    float s = b1[m];
#pragma unroll 8
    for (int kc = 0; kc < 32; ++kc)
        s += part[(size_t)(kc * 256 + m) * B_ + bl];
    res1T[m * B_ + bl] = fmaxf(s, 0.f);
}

// ---------------------------------------------------------------------------
// Kernel 4: res2 = res1@w2.T+b2 ; out = res2@w3.T+b3. 1 block/batch row.
// ---------------------------------------------------------------------------
__global__ __launch_bounds__(512, 2) void head_k(
    const float* __restrict__ res1T, const float* __restrict__ w2,
    const float* __restrict__ b2, const float* __restrict__ w3,
    const float* __restrict__ b3, float* __restrict__ out) {
    __shared__ float r1s[256];
    __shared__ float r2s[512];
    const int tid = threadIdx.x;
    const int b   = blockIdx.x;

    if (tid < 256) r1s[tid] = res1T[tid * B_ + b];
    __syncthreads();
    {
        float s = b2[tid];
        const float* wr = &w2[tid * 256];
#pragma unroll 4
        for (int k = 0; k < 256; k += 4) {
            float4 w = *(const float4*)&wr[k];
            s += r1s[k] * w.x + r1s[k + 1] * w.y + r1s[k + 2] * w.z + r1s[k + 3] * w.w;
        }
        r2s[tid] = s;
    }
    __syncthreads();
    if (tid < 64) {
        float s = b3[tid];
        const float* wr = &w3[tid * 512];
#pragma unroll 4
        for (int k = 0; k < 512; k += 4) {
            float4 w = *(const float4*)&wr[k];
            s += r2s[k] * w.x + r2s[k + 1] * w.y + r2s[k + 2] * w.z + r2s[k + 3] * w.w;
        }
        out[b * 64 + tid] = s;
    }
}

extern "C" void kernel_launch(void* const* d_in, const int* in_sizes, int n_in,
                              void* d_out, int out_size, void* d_ws, size_t ws_size,
                              hipStream_t stream) {
    (void)in_sizes; (void)n_in; (void)out_size; (void)ws_size;
    const float* x    = (const float*)d_in[0];
    const float* w_ih = (const float*)d_in[1];
    const float* w_hh = (const float*)d_in[2];
    const float* b_ih = (const float*)d_in[3];
    const float* b_hh = (const float*)d_in[4];
    const float* w1   = (const float*)d_in[5];
    const float* b1   = (const float*)d_in[6];
    const float* w2   = (const float*)d_in[7];
    const float* b2   = (const float*)d_in[8];
    const float* w3   = (const float*)d_in[9];
    const float* b3   = (const float*)d_in[10];
    float* out = (float*)d_out;

    unsigned int* hT_p  = (unsigned int*)d_ws;                            // 32 MB
    float*        part  = (float*)((char*)d_ws + ((size_t)32 << 20));     // 4 MB
    float*        res1T = (float*)((char*)d_ws + ((size_t)40 << 20));     // 128 KB

    const size_t smem1 = 147456 + 1024 + 4096;  // 152,576 B
    (void)hipFuncSetAttribute((const void*)lstm_k,
                              hipFuncAttributeMaxDynamicSharedMemorySize, (int)smem1);

    hipLaunchKernelGGL(lstm_k, dim3(B_), dim3(NTH), smem1, stream,
                       x, w_ih, w_hh, b_ih, b_hh, hT_p);
    hipLaunchKernelGGL(gemm1_k, dim3(16, 32), dim3(256), 0, stream, hT_p, w1, part);
    hipLaunchKernelGGL(reduce_k, dim3(256), dim3(128), 0, stream, part, b1, res1T);
    hipLaunchKernelGGL(head_k, dim3(B_), dim3(512), 0, stream,
                       res1T, w2, b2, w3, b3, out);
}

// Round 11
// 2301.215 us; speedup vs baseline: 1.2634x; 1.2634x over previous
//
#include <hip/hip_runtime.h>
#include <hip/hip_fp16.h>

#define B_    128
#define T_    1024
#define NTH   512
#define NVP   36   // f16 pairs per row in arch VGPRs (pairs   0..35, h-quads 0..8)
#define NAP   64   // f16 pairs per row in AGPRs      (pairs  36..99, h-quads 9..24)
#define NLP   28   // f16 pairs per row in LDS        (pairs 100..127, h-quads 25..31)
#define NQLDS 7    // LDS quads per row

typedef _Float16 half2_t __attribute__((ext_vector_type(2)));

__device__ __forceinline__ float fdot2(unsigned int w, unsigned int h, float acc) {
    return __builtin_amdgcn_fdot2(__builtin_bit_cast(half2_t, w),
                                  __builtin_bit_cast(half2_t, h), acc, false);
}
__device__ __forceinline__ unsigned int packf16(float a, float b) {
    half2_t h;
    h.x = (_Float16)a;
    h.y = (_Float16)b;
    return __builtin_bit_cast(unsigned int, h);
}
// Explicit AGPR residency. VOP3P v_dot2 can NOT source "a" regs (round 8);
// bounce through v_accvgpr_read. Latency hidden by the 2nd wave per SIMD.
#define AGPR_WRITE(dst, src) \
    asm volatile("v_accvgpr_write_b32 %0, %1" : "=a"(dst) : "v"(src))
#define AGPR_READ(dst, src) \
    asm volatile("v_accvgpr_read_b32 %0, %1" : "=v"(dst) : "a"(src))

// ---------------------------------------------------------------------------
// Kernel 1: persistent LSTM. 1 block/batch, 512 threads = 8 waves = 2/SIMD
// (latency hiding -- round 10's 1-wave config exposed every AGPR/DS stall).
// Thread owns rows tid (i/f gate) and tid+512 (g/o gate). Per-wave budget at
// 2 waves/SIMD is 256 unified regs: 72 arch weights + 128 AGPR weights
// (exactly the AGPR half) + 28 pairs/row in LDS (112 KB). Gate exchange via
// LDS, 2 barriers/step.
// ---------------------------------------------------------------------------
__global__ __attribute__((amdgpu_flat_work_group_size(NTH, NTH),
                          amdgpu_waves_per_eu(2, 2)))
void lstm_k(const float* __restrict__ x, const float* __restrict__ w_ih,
            const float* __restrict__ w_hh, const float* __restrict__ b_ih,
            const float* __restrict__ b_hh, unsigned int* __restrict__ hT_p) {
    extern __shared__ unsigned char smem[];
    uint4*        w_lds4 = (uint4*)smem;                        // [14][512] quads = 112 KB
    unsigned int* hbuf   = (unsigned int*)(smem + 114688);      // [2][128] packed f16 pairs
    float*        gates  = (float*)(smem + 114688 + 1024);      // [1024]
    float*        xseq   = (float*)(smem + 114688 + 1024 + 4096); // [1024]

    const int tid = threadIdx.x;
    const int b   = blockIdx.x;
    const int r0  = tid;          // rows 0..511   = i (u<256) / f (u>=256)
    const int r1  = tid + 512;    // rows 512..1023 = g / o

    const float bs0 = b_ih[r0] + b_hh[r0], wi0 = w_ih[r0];
    const float bs1 = b_ih[r1] + b_hh[r1], wi1 = w_ih[r1];

    // xseq[t] = x[b, (t%512)*2 + t/512]
    for (int t = tid; t < T_; t += NTH)
        xseq[t] = x[b * T_ + ((t & 511) << 1) + (t >> 9)];

    // ---- arch-VGPR weights: pairs [0, NVP) of each row ----
    unsigned int wv0[NVP], wv1[NVP];
#pragma unroll
    for (int p = 0; p < NVP; p += 2) {
        float4 a4 = *(const float4*)&w_hh[(size_t)r0 * 256 + 2 * p];
        wv0[p] = packf16(a4.x, a4.y); wv0[p + 1] = packf16(a4.z, a4.w);
        float4 c4 = *(const float4*)&w_hh[(size_t)r1 * 256 + 2 * p];
        wv1[p] = packf16(c4.x, c4.y); wv1[p + 1] = packf16(c4.z, c4.w);
    }
    // ---- AGPR weights: pairs [NVP, NVP+NAP) ----
    unsigned int wa0[NAP], wa1[NAP];
#pragma unroll
    for (int p = 0; p < NAP; p += 2) {
        float4 a4 = *(const float4*)&w_hh[(size_t)r0 * 256 + 2 * (NVP + p)];
        unsigned int t0 = packf16(a4.x, a4.y), t1 = packf16(a4.z, a4.w);
        AGPR_WRITE(wa0[p], t0);
        AGPR_WRITE(wa0[p + 1], t1);
        float4 c4 = *(const float4*)&w_hh[(size_t)r1 * 256 + 2 * (NVP + p)];
        unsigned int t2 = packf16(c4.x, c4.y), t3 = packf16(c4.z, c4.w);
        AGPR_WRITE(wa1[p], t2);
        AGPR_WRITE(wa1[p + 1], t3);
    }
    // ---- LDS weights: pairs [NVP+NAP, 128) -> quad (r*NQLDS+j), lane tid ----
#pragma unroll
    for (int r = 0; r < 2; ++r) {
        const size_t row = (size_t)(r ? r1 : r0) * 256;
#pragma unroll
        for (int j = 0; j < NQLDS; ++j) {
            const float* src = &w_hh[row + 2 * (NVP + NAP) + 8 * j];
            float4 a4 = ((const float4*)src)[0];
            float4 c4 = ((const float4*)src)[1];
            uint4 pk;
            pk.x = packf16(a4.x, a4.y); pk.y = packf16(a4.z, a4.w);
            pk.z = packf16(c4.x, c4.y); pk.w = packf16(c4.z, c4.w);
            w_lds4[(r * NQLDS + j) * NTH + tid] = pk;
        }
    }
    if (tid < 128) { hbuf[tid] = 0u; hbuf[128 + tid] = 0u; }
    float c_state = 0.f;
    __syncthreads();

    for (int t = 0; t < T_; ++t) {
        const uint4* h4 = (const uint4*)&hbuf[(t & 1) * 128];
        const float  xt = xseq[t];
        float a00 = fmaf(xt, wi0, bs0), a01 = 0.f;   // row r0 chains
        float a10 = fmaf(xt, wi1, bs1), a11 = 0.f;   // row r1 chains
        // --- VGPR part: quads 0..8 ---
#pragma unroll
        for (int q = 0; q < 9; ++q) {
            uint4 hp = h4[q];
            a00 = fdot2(wv0[4 * q + 0], hp.x, a00);
            a01 = fdot2(wv0[4 * q + 1], hp.y, a01);
            a10 = fdot2(wv1[4 * q + 0], hp.x, a10);
            a11 = fdot2(wv1[4 * q + 1], hp.y, a11);
            a00 = fdot2(wv0[4 * q + 2], hp.z, a00);
            a01 = fdot2(wv0[4 * q + 3], hp.w, a01);
            a10 = fdot2(wv1[4 * q + 2], hp.z, a10);
            a11 = fdot2(wv1[4 * q + 3], hp.w, a11);
        }
        __builtin_amdgcn_sched_barrier(0);
        // --- AGPR part: quads 9..24, in 4-quad windows ---
#pragma unroll
        for (int w = 0; w < 4; ++w) {
#pragma unroll
            for (int qq = 0; qq < 4; ++qq) {
                const int q = 4 * w + qq;           // 0..15
                uint4 hp = h4[9 + q];
                unsigned int t0, t1, t2, t3;
                AGPR_READ(t0, wa0[4 * q + 0]);
                a00 = fdot2(t0, hp.x, a00);
                AGPR_READ(t1, wa0[4 * q + 1]);
                a01 = fdot2(t1, hp.y, a01);
                AGPR_READ(t2, wa1[4 * q + 0]);
                a10 = fdot2(t2, hp.x, a10);
                AGPR_READ(t3, wa1[4 * q + 1]);
                a11 = fdot2(t3, hp.y, a11);
                AGPR_READ(t0, wa0[4 * q + 2]);
                a00 = fdot2(t0, hp.z, a00);
                AGPR_READ(t1, wa0[4 * q + 3]);
                a01 = fdot2(t1, hp.w, a01);
                AGPR_READ(t2, wa1[4 * q + 2]);
                a10 = fdot2(t2, hp.z, a10);
                AGPR_READ(t3, wa1[4 * q + 3]);
                a11 = fdot2(t3, hp.w, a11);
            }
            __builtin_amdgcn_sched_barrier(0);
        }
        // --- LDS part: quads 25..31 ---
#pragma unroll
        for (int j = 0; j < NQLDS; ++j) {
            uint4 hp = h4[25 + j];
            uint4 w0 = w_lds4[j * NTH + tid];
            uint4 w1 = w_lds4[(NQLDS + j) * NTH + tid];
            a00 = fdot2(w0.x, hp.x, a00);
            a01 = fdot2(w0.y, hp.y, a01);
            a10 = fdot2(w1.x, hp.x, a10);
            a11 = fdot2(w1.y, hp.y, a11);
            a00 = fdot2(w0.z, hp.z, a00);
            a01 = fdot2(w0.w, hp.w, a01);
            a10 = fdot2(w1.z, hp.z, a10);
            a11 = fdot2(w1.w, hp.w, a11);
        }
        gates[r0] = a00 + a01;      // rows 0..511   (i | f)
        gates[r1] = a10 + a11;      // rows 512..1023 (g | o)
        __syncthreads();
        const int nxt = ((t + 1) & 1) * 128;
        if (tid < 256) {
            const float gi = gates[tid],       gf = gates[256 + tid];
            const float gg = gates[512 + tid], go = gates[768 + tid];
            const float i_ = __builtin_amdgcn_rcpf(1.f + __expf(-gi));
            const float f_ = __builtin_amdgcn_rcpf(1.f + __expf(-gf));
            const float g_ = 1.f - 2.f * __builtin_amdgcn_rcpf(__expf(2.f * gg) + 1.f);
            const float o_ = __builtin_amdgcn_rcpf(1.f + __expf(-go));
            c_state = f_ * c_state + i_ * g_;
            const float h = o_ * (1.f - 2.f * __builtin_amdgcn_rcpf(__expf(2.f * c_state) + 1.f));
            ((__half*)&hbuf[nxt])[tid] = __float2half(h);
        }
        __syncthreads();
        if (t >= 512 && tid < 128)
            hT_p[(size_t)(((t - 512) << 7) + tid) * B_ + b] = hbuf[nxt + tid];
    }
}

// ---------------------------------------------------------------------------
// Kernel 2: res1 partials, LDS-staged. Grid (16 m-tiles, 32 k-splits),
// 256 threads. w1 packed f16 in LDS; reads wave-uniform b128 broadcasts.
// h reads coalesced. part[(ks*256+m)*128+b].
// ---------------------------------------------------------------------------
#define WST 260
__global__ __launch_bounds__(256, 2) void gemm1_k(
    const unsigned int* __restrict__ hT_p, const float* __restrict__ w1,
    float* __restrict__ part) {
    __shared__ unsigned int w_stage[16 * WST];   // 16.6 KB

    const int tid = threadIdx.x;
    const int m0  = blockIdx.x * 16;
    const int ks  = blockIdx.y;                  // 0..31
    const int bl  = tid & 127;
    const int mg  = tid >> 7;                    // wave-uniform
    const int srow = tid >> 4, slane = tid & 15;

    float acc[8];
#pragma unroll
    for (int j = 0; j < 8; ++j) acc[j] = 0.f;

    const int kbase = ks * 2048;
    for (int s = 0; s < 8; ++s) {
        const int k0 = kbase + s * 256;
        __syncthreads();
        const float* wrow = &w1[(size_t)(m0 + srow) * 131072 + 2 * k0];
#pragma unroll
        for (int i = 0; i < 8; ++i) {
            const int f = slane + 16 * i;
            float4 v = *(const float4*)&wrow[4 * f];
            w_stage[srow * WST + 2 * f]     = packf16(v.x, v.y);
            w_stage[srow * WST + 2 * f + 1] = packf16(v.z, v.w);
        }
        __syncthreads();
#pragma unroll 4
        for (int kg = 0; kg < 64; ++kg) {
            const int kp = 4 * kg;
            unsigned int h0 = hT_p[(size_t)(k0 + kp) * B_ + bl];
            unsigned int h1 = hT_p[(size_t)(k0 + kp + 1) * B_ + bl];
            unsigned int h2 = hT_p[(size_t)(k0 + kp + 2) * B_ + bl];
            unsigned int h3 = hT_p[(size_t)(k0 + kp + 3) * B_ + bl];
#pragma unroll
            for (int j = 0; j < 8; ++j) {
                uint4 w = *(const uint4*)&w_stage[(mg * 8 + j) * WST + kp];
                acc[j] = fdot2(w.x, h0, acc[j]);
                acc[j] = fdot2(w.y, h1, acc[j]);
                acc[j] = fdot2(w.z, h2, acc[j]);
                acc[j] = fdot2(w.w, h3, acc[j]);
            }
        }
    }
#pragma unroll
    for (int j = 0; j < 8; ++j)
        part[(size_t)(ks * 256 + m0 + mg * 8 + j) * B_ + bl] = acc[j];
}

// ---------------------------------------------------------------------------
// Kernel 3: reduce partials over 32 k-splits (+b1, ReLU) -> res1T[m*128+b].
// ---------------------------------------------------------------------------
__global__ __launch_bounds__(128, 8) void reduce_k(
    const float* __restrict__ part, const float* __restrict__ b1,
    float* __restrict__ res1T) {
    const int m = blockIdx.x, bl = threadIdx.x;
    float s = b1[m];
#pragma unroll 8
    for (int kc = 0; kc < 32; ++kc)
        s += part[(size_t)(kc * 256 + m) * B_ + bl];
    res1T[m * B_ + bl] = fmaxf(s, 0.f);
}

// ---------------------------------------------------------------------------
// Kernel 4: res2 = res1@w2.T+b2 ; out = res2@w3.T+b3. 1 block/batch row.
// ---------------------------------------------------------------------------
__global__ __launch_bounds__(512, 2) void head_k(
    const float* __restrict__ res1T, const float* __restrict__ w2,
    const float* __restrict__ b2, const float* __restrict__ w3,
    const float* __restrict__ b3, float* __restrict__ out) {
    __shared__ float r1s[256];
    __shared__ float r2s[512];
    const int tid = threadIdx.x;
    const int b   = blockIdx.x;

    if (tid < 256) r1s[tid] = res1T[tid * B_ + b];
    __syncthreads();
    {
        float s = b2[tid];
        const float* wr = &w2[tid * 256];
#pragma unroll 4
        for (int k = 0; k < 256; k += 4) {
            float4 w = *(const float4*)&wr[k];
            s += r1s[k] * w.x + r1s[k + 1] * w.y + r1s[k + 2] * w.z + r1s[k + 3] * w.w;
        }
        r2s[tid] = s;
    }
    __syncthreads();
    if (tid < 64) {
        float s = b3[tid];
        const float* wr = &w3[tid * 512];
#pragma unroll 4
        for (int k = 0; k < 512; k += 4) {
            float4 w = *(const float4*)&wr[k];
            s += r2s[k] * w.x + r2s[k + 1] * w.y + r2s[k + 2] * w.z + r2s[k + 3] * w.w;
        }
        out[b * 64 + tid] = s;
    }
}

extern "C" void kernel_launch(void* const* d_in, const int* in_sizes, int n_in,
                              void* d_out, int out_size, void* d_ws, size_t ws_size,
                              hipStream_t stream) {
    (void)in_sizes; (void)n_in; (void)out_size; (void)ws_size;
    const float* x    = (const float*)d_in[0];
    const float* w_ih = (const float*)d_in[1];
    const float* w_hh = (const float*)d_in[2];
    const float* b_ih = (const float*)d_in[3];
    const float* b_hh = (const float*)d_in[4];
    const float* w1   = (const float*)d_in[5];
    const float* b1   = (const float*)d_in[6];
    const float* w2   = (const float*)d_in[7];
    const float* b2   = (const float*)d_in[8];
    const float* w3   = (const float*)d_in[9];
    const float* b3   = (const float*)d_in[10];
    float* out = (float*)d_out;

    unsigned int* hT_p  = (unsigned int*)d_ws;                            // 32 MB
    float*        part  = (float*)((char*)d_ws + ((size_t)32 << 20));     // 4 MB
    float*        res1T = (float*)((char*)d_ws + ((size_t)40 << 20));     // 128 KB

    const size_t smem1 = 114688 + 1024 + 4096 + 4096;  // 123,904 B
    (void)hipFuncSetAttribute((const void*)lstm_k,
                              hipFuncAttributeMaxDynamicSharedMemorySize, (int)smem1);

    hipLaunchKernelGGL(lstm_k, dim3(B_), dim3(NTH), smem1, stream,
                       x, w_ih, w_hh, b_ih, b_hh, hT_p);
    hipLaunchKernelGGL(gemm1_k, dim3(16, 32), dim3(256), 0, stream, hT_p, w1, part);
    hipLaunchKernelGGL(reduce_k, dim3(256), dim3(128), 0, stream, part, b1, res1T);
    hipLaunchKernelGGL(head_k, dim3(B_), dim3(512), 0, stream,
                       res1T, w2, b2, w3, b3, out);
}

// Round 12
// 2271.206 us; speedup vs baseline: 1.2801x; 1.0132x over previous
//
#include <hip/hip_runtime.h>
#include <hip/hip_fp16.h>

#define B_    128
#define T_    1024
#define NTH   512

// LDS byte offsets (lstm_k)
#define SA_OFF 0        // streamed A frags: [8 waves][16 frags][64 lanes] x 16B = 128 KB
#define HB_OFF 131072   // h double buffer: 2 x 128 dwords (packed f16 pairs) = 1 KB
#define GT_OFF 132096   // gates: 1024 f32 = 4 KB
#define XS_OFF 136192   // xseq: 1024 f32 = 4 KB
#define SM_TOT 140288

typedef _Float16 half2_t __attribute__((ext_vector_type(2)));
typedef _Float16 half8   __attribute__((ext_vector_type(8)));
typedef float    f32x4   __attribute__((ext_vector_type(4)));

__device__ __forceinline__ float fdot2(unsigned int w, unsigned int h, float acc) {
    return __builtin_amdgcn_fdot2(__builtin_bit_cast(half2_t, w),
                                  __builtin_bit_cast(half2_t, h), acc, false);
}
__device__ __forceinline__ unsigned int packf16(float a, float b) {
    half2_t h;
    h.x = (_Float16)a;
    h.y = (_Float16)b;
    return __builtin_bit_cast(unsigned int, h);
}
__device__ __forceinline__ half8 pack8(const float* p) {
    half8 r;
#pragma unroll
    for (int i = 0; i < 8; ++i) r[i] = (_Float16)p[i];
    return r;
}

// ---------------------------------------------------------------------------
// Kernel 1: persistent LSTM via MFMA. 1 block/batch, 512 threads = 8 waves
// (2/SIMD). gates(1024) = W_hh(1024x256) @ h(256) per step, computed as
// 16x16x32_f16 MFMAs with B = h-chunk replicated across all 16 columns
// (=> D column-replicated; lanes l&15==0 extract). Wave w owns rows
// w*128..w*128+127 = 8 row-groups of 16. A frags: k-chunks 0..5 resident in
// regs (192 dw; MFMA reads AGPR directly - no accvgpr_read), k-chunks 6,7
// streamed from lane-private LDS slots (128 KB, conflict-free).
// C (8 x f32x4 = 32) accumulates in AGPRs. Activation by threads tid<256.
// ---------------------------------------------------------------------------
__global__ __attribute__((amdgpu_flat_work_group_size(NTH, NTH),
                          amdgpu_waves_per_eu(2, 2)))
void lstm_k(const float* __restrict__ x, const float* __restrict__ w_ih,
            const float* __restrict__ w_hh, const float* __restrict__ b_ih,
            const float* __restrict__ b_hh, unsigned int* __restrict__ hT_p) {
    extern __shared__ unsigned char smem[];
    char*         sA     = (char*)smem + SA_OFF;
    unsigned int* hbuf_d = (unsigned int*)(smem + HB_OFF);   // [2][128] packed pairs
    float*        gates  = (float*)(smem + GT_OFF);          // [1024]
    float*        xseq   = (float*)(smem + XS_OFF);          // [1024]

    const int tid   = threadIdx.x;
    const int b     = blockIdx.x;
    const int l     = tid & 63;
    const int w     = tid >> 6;          // wave 0..7
    const int g     = l >> 4;            // lane group 0..3
    const int r16   = l & 15;            // row within 16-row group
    const int wbase = w * 128;           // this wave's first gate row

    // activation-thread constants (tid < 256 only uses them)
    float bs[4], wi[4];
#pragma unroll
    for (int gg = 0; gg < 4; ++gg) {
        const int r = gg * 256 + (tid & 255);
        bs[gg] = b_ih[r] + b_hh[r];
        wi[gg] = w_ih[r];
    }

    // xseq[t] = x[b, (t%512)*2 + t/512]
    for (int t = tid; t < T_; t += NTH)
        xseq[t] = x[b * T_ + ((t & 511) << 1) + (t >> 9)];

    // ---- resident A frags: k-chunks 0..5, row-groups 0..7 ----
    // lane l holds A rows wbase+rg*16+r16, k = kc*32 + g*8 .. +7
    half8 ar[6][8];
#pragma unroll
    for (int kc = 0; kc < 6; ++kc)
#pragma unroll
        for (int rg = 0; rg < 8; ++rg)
            ar[kc][rg] = pack8(&w_hh[(size_t)(wbase + rg * 16 + r16) * 256 + kc * 32 + g * 8]);

    // ---- streamed A frags: k-chunks 6,7 -> lane-private LDS slots ----
    char* sAth = sA + w * 16384 + l * 16;
#pragma unroll
    for (int f = 0; f < 16; ++f) {
        const int kc = 6 + (f >> 3), rg = f & 7;
        half8 a = pack8(&w_hh[(size_t)(wbase + rg * 16 + r16) * 256 + kc * 32 + g * 8]);
        *(half8*)(sAth + f * 1024) = a;
    }
    if (tid < 256) hbuf_d[tid] = 0u;     // zero both h buffers
    float c_state = 0.f;
    __syncthreads();

    for (int t = 0; t < T_; ++t) {
        const char* hcur = (const char*)hbuf_d + (t & 1) * 512;
        f32x4 c8[8];
#pragma unroll
        for (int rg = 0; rg < 8; ++rg) c8[rg] = (f32x4){0.f, 0.f, 0.f, 0.f};

        // resident k-chunks 0..5
#pragma unroll
        for (int kc = 0; kc < 6; ++kc) {
            half8 bf = *(const half8*)(hcur + kc * 64 + g * 16);  // h[k], k=kc*32+g*8..+7
#pragma unroll
            for (int rg = 0; rg < 8; ++rg)
                c8[rg] = __builtin_amdgcn_mfma_f32_16x16x32_f16(ar[kc][rg], bf, c8[rg], 0, 0, 0);
        }
        // streamed k-chunks 6,7
#pragma unroll
        for (int s = 0; s < 2; ++s) {
            half8 bf = *(const half8*)(hcur + (6 + s) * 64 + g * 16);
#pragma unroll
            for (int rg = 0; rg < 8; ++rg) {
                half8 af = *(const half8*)(sAth + (s * 8 + rg) * 1024);
                c8[rg] = __builtin_amdgcn_mfma_f32_16x16x32_f16(af, bf, c8[rg], 0, 0, 0);
            }
        }
        // D is column-replicated; col-0 lanes write rows wbase+rg*16+g*4+{0..3}
        if ((l & 15) == 0) {
#pragma unroll
            for (int rg = 0; rg < 8; ++rg)
                *(f32x4*)&gates[wbase + rg * 16 + g * 4] = c8[rg];
        }
        __syncthreads();
        const int nxt = ((t + 1) & 1) * 128;   // dword offset in hbuf_d
        if (tid < 256) {
            const int   u  = tid;
            const float xt = xseq[t];
            const float gi = gates[u]       + bs[0] + xt * wi[0];
            const float gf = gates[256 + u] + bs[1] + xt * wi[1];
            const float gg = gates[512 + u] + bs[2] + xt * wi[2];
            const float go = gates[768 + u] + bs[3] + xt * wi[3];
            const float i_ = __builtin_amdgcn_rcpf(1.f + __expf(-gi));
            const float f_ = __builtin_amdgcn_rcpf(1.f + __expf(-gf));
            const float g_ = 1.f - 2.f * __builtin_amdgcn_rcpf(__expf(2.f * gg) + 1.f);
            const float o_ = __builtin_amdgcn_rcpf(1.f + __expf(-go));
            c_state = f_ * c_state + i_ * g_;
            const float h = o_ * (1.f - 2.f * __builtin_amdgcn_rcpf(__expf(2.f * c_state) + 1.f));
            ((__half*)&hbuf_d[nxt])[u] = __float2half(h);
        }
        __syncthreads();
        if (t >= 512 && tid < 128)
            hT_p[(size_t)(((t - 512) << 7) + tid) * B_ + b] = hbuf_d[nxt + tid];
    }
}

// ---------------------------------------------------------------------------
// Kernel 2: res1 partials, LDS-staged. Grid (16 m-tiles, 32 k-splits),
// 256 threads. w1 packed f16 in LDS; reads wave-uniform b128 broadcasts.
// h reads coalesced. part[(ks*256+m)*128+b].
// ---------------------------------------------------------------------------
#define WST 260
__global__ __launch_bounds__(256, 2) void gemm1_k(
    const unsigned int* __restrict__ hT_p, const float* __restrict__ w1,
    float* __restrict__ part) {
    __shared__ unsigned int w_stage[16 * WST];   // 16.6 KB

    const int tid = threadIdx.x;
    const int m0  = blockIdx.x * 16;
    const int ks  = blockIdx.y;                  // 0..31
    const int bl  = tid & 127;
    const int mg  = tid >> 7;                    // wave-uniform
    const int srow = tid >> 4, slane = tid & 15;

    float acc[8];
#pragma unroll
    for (int j = 0; j < 8; ++j) acc[j] = 0.f;

    const int kbase = ks * 2048;
    for (int s = 0; s < 8; ++s) {
        const int k0 = kbase + s * 256;
        __syncthreads();
        const float* wrow = &w1[(size_t)(m0 + srow) * 131072 + 2 * k0];
#pragma unroll
        for (int i = 0; i < 8; ++i) {
            const int f = slane + 16 * i;
            float4 v = *(const float4*)&wrow[4 * f];
            w_stage[srow * WST + 2 * f]     = packf16(v.x, v.y);
            w_stage[srow * WST + 2 * f + 1] = packf16(v.z, v.w);
        }
        __syncthreads();
#pragma unroll 4
        for (int kg = 0; kg < 64; ++kg) {
            const int kp = 4 * kg;
            unsigned int h0 = hT_p[(size_t)(k0 + kp) * B_ + bl];
            unsigned int h1 = hT_p[(size_t)(k0 + kp + 1) * B_ + bl];
            unsigned int h2 = hT_p[(size_t)(k0 + kp + 2) * B_ + bl];
            unsigned int h3 = hT_p[(size_t)(k0 + kp + 3) * B_ + bl];
#pragma unroll
            for (int j = 0; j < 8; ++j) {
                uint4 w = *(const uint4*)&w_stage[(mg * 8 + j) * WST + kp];
                acc[j] = fdot2(w.x, h0, acc[j]);
                acc[j] = fdot2(w.y, h1, acc[j]);
                acc[j] = fdot2(w.z, h2, acc[j]);
                acc[j] = fdot2(w.w, h3, acc[j]);
            }
        }
    }
#pragma unroll
    for (int j = 0; j < 8; ++j)
        part[(size_t)(ks * 256 + m0 + mg * 8 + j) * B_ + bl] = acc[j];
}

// ---------------------------------------------------------------------------
// Kernel 3: reduce partials over 32 k-splits (+b1, ReLU) -> res1T[m*128+b].
// ---------------------------------------------------------------------------
__global__ __launch_bounds__(128, 8) void reduce_k(
    const float* __restrict__ part, const float* __restrict__ b1,
    float* __restrict__ res1T) {
    const int m = blockIdx.x, bl = threadIdx.x;
    float s = b1[m];
#pragma unroll 8
    for (int kc = 0; kc < 32; ++kc)
        s += part[(size_t)(kc * 256 + m) * B_ + bl];
    res1T[m * B_ + bl] = fmaxf(s, 0.f);
}

// ---------------------------------------------------------------------------
// Kernel 4: res2 = res1@w2.T+b2 ; out = res2@w3.T+b3. 1 block/batch row.
// ---------------------------------------------------------------------------
__global__ __launch_bounds__(512, 2) void head_k(
    const float* __restrict__ res1T, const float* __restrict__ w2,
    const float* __restrict__ b2, const float* __restrict__ w3,
    const float* __restrict__ b3, float* __restrict__ out) {
    __shared__ float r1s[256];
    __shared__ float r2s[512];
    const int tid = threadIdx.x;
    const int b   = blockIdx.x;

    if (tid < 256) r1s[tid] = res1T[tid * B_ + b];
    __syncthreads();
    {
        float s = b2[tid];
        const float* wr = &w2[tid * 256];
#pragma unroll 4
        for (int k = 0; k < 256; k += 4) {
            float4 w = *(const float4*)&wr[k];
            s += r1s[k] * w.x + r1s[k + 1] * w.y + r1s[k + 2] * w.z + r1s[k + 3] * w.w;
        }
        r2s[tid] = s;
    }
    __syncthreads();
    if (tid < 64) {
        float s = b3[tid];
        const float* wr = &w3[tid * 512];
#pragma unroll 4
        for (int k = 0; k < 512; k += 4) {
            float4 w = *(const float4*)&wr[k];
            s += r2s[k] * w.x + r2s[k + 1] * w.y + r2s[k + 2] * w.z + r2s[k + 3] * w.w;
        }
        out[b * 64 + tid] = s;
    }
}

extern "C" void kernel_launch(void* const* d_in, const int* in_sizes, int n_in,
                              void* d_out, int out_size, void* d_ws, size_t ws_size,
                              hipStream_t stream) {
    (void)in_sizes; (void)n_in; (void)out_size; (void)ws_size;
    const float* x    = (const float*)d_in[0];
    const float* w_ih = (const float*)d_in[1];
    const float* w_hh = (const float*)d_in[2];
    const float* b_ih = (const float*)d_in[3];
    const float* b_hh = (const float*)d_in[4];
    const float* w1   = (const float*)d_in[5];
    const float* b1   = (const float*)d_in[6];
    const float* w2   = (const float*)d_in[7];
    const float* b2   = (const float*)d_in[8];
    const float* w3   = (const float*)d_in[9];
    const float* b3   = (const float*)d_in[10];
    float* out = (float*)d_out;

    unsigned int* hT_p  = (unsigned int*)d_ws;                            // 32 MB
    float*        part  = (float*)((char*)d_ws + ((size_t)32 << 20));     // 4 MB
    float*        res1T = (float*)((char*)d_ws + ((size_t)40 << 20));     // 128 KB

    (void)hipFuncSetAttribute((const void*)lstm_k,
                              hipFuncAttributeMaxDynamicSharedMemorySize, SM_TOT);

    hipLaunchKernelGGL(lstm_k, dim3(B_), dim3(NTH), SM_TOT, stream,
                       x, w_ih, w_hh, b_ih, b_hh, hT_p);
    hipLaunchKernelGGL(gemm1_k, dim3(16, 32), dim3(256), 0, stream, hT_p, w1, part);
    hipLaunchKernelGGL(reduce_k, dim3(256), dim3(128), 0, stream, part, b1, res1T);
    hipLaunchKernelGGL(head_k, dim3(B_), dim3(512), 0, stream,
                       res1T, w2, b2, w3, b3, out);
}